// Round 14
// baseline (308.738 us; speedup 1.0000x reference)
//
#include <hip/hip_runtime.h>

#define DSX 60
#define SZ  64
#define NPT (DSX*SZ*SZ)        // 245760 points
#define NS_P 64
#define NS_Q 68
#define NS_R 68
#define NS_SZ (NS_P*NS_Q*NS_R) // 295936
#define P_PER_ROW 61440        // 245760/4 (float4 groups per W1 row)
#define KSPLIT 8
#define P_CHUNK (P_PER_ROW / KSPLIT)   // 7680
#define PB_SLAB (15*NS_Q*NS_R)         // 69360 (row-batch stride in PB)
#define NS_BLOCKS 1156                 // ceil(NS_SZ/256)
#define TR_BLOCKS (NPT / 64)           // 3840
#define PT_BLOCKS (NPT / 256)          // 960

typedef float fx4 __attribute__((ext_vector_type(4)));

__device__ __forceinline__ unsigned rne_bf16(float x) {
    unsigned b = __float_as_uint(x);
    return (b + 0x7fffu + ((b >> 16) & 1u)) >> 16;   // round-to-nearest-even bf16
}

// ---------------- fused prologue:
// blocks [0, NS_BLOCKS): PB0 = channel-sum(vinput) in ns layout; PB1 = 0
// blocks [NS_BLOCKS, NS_BLOCKS+TR_BLOCKS): syn transpose+pack to bf16 g-major
__global__ __launch_bounds__(256) void prologue(const float* __restrict__ vin,
                                                const float* __restrict__ syn,
                                                float* __restrict__ PB0,
                                                float* __restrict__ PB1,
                                                uint2* __restrict__ synP) {
    if (blockIdx.x < NS_BLOCKS) {
        int t = blockIdx.x * 256 + threadIdx.x;
        if (t >= NS_SZ) return;
        int r = t % NS_R;
        int q = (t / NS_R) % NS_Q;
        int p = t / (NS_R * NS_Q);
        float val = 0.f;
        if (p >= 2 && p < 62 && q >= 2 && q < 66 && r >= 2 && r < 66) {
            const float* b = vin + ((((size_t)(p - 2) * SZ) + (q - 2)) * SZ + (r - 2)) * 4;
            val = (b[0] + b[1]) + (b[2] + b[3]);
        }
        PB0[t] = val;
        PB1[t] = 0.f;
    } else {
        __shared__ float tile[64 * 65];
        int t0 = (blockIdx.x - NS_BLOCKS) * 64;
        const fx4* s4 = (const fx4*)syn;
#pragma unroll
        for (int r = 0; r < 4; r++) {
            int idx = r * 256 + threadIdx.x;      // 0..1023
            int pl = idx >> 4, g = idx & 15;
            fx4 v = s4[(size_t)(t0 + pl) * 16 + g];
            int base = pl * 65 + g * 4;
            tile[base] = v.x; tile[base + 1] = v.y; tile[base + 2] = v.z; tile[base + 3] = v.w;
        }
        __syncthreads();
        int l = threadIdx.x & 63;
        int wv = threadIdx.x >> 6; // 0..3
#pragma unroll
        for (int r = 0; r < 4; r++) {
            int g = r * 4 + wv;
            int base = l * 65 + g * 4;
            uint2 u;
            u.x = rne_bf16(tile[base])     | (rne_bf16(tile[base + 1]) << 16);
            u.y = rne_bf16(tile[base + 2]) | (rne_bf16(tile[base + 3]) << 16);
            synP[(size_t)g * NPT + t0 + l] = u;
        }
    }
}

// ---------------- conv: core = <bf16 weights, PBin neighborhood>, coalesced 8B weight loads
// PBout interior = 4 * 0.9 * relu(core)  (borders untouched -> stay 0)
__global__ __launch_bounds__(256) void conv_kernel(const float* __restrict__ PBin,
                                                   const uint2* __restrict__ synP,
                                                   float* __restrict__ PBout) {
    int t = blockIdx.x * 256 + threadIdx.x;   // 960 blocks exactly covers NPT
    int k = t & 63;
    int j = (t >> 6) & 63;
    int i = t >> 12;
    float acc = 0.f;
#pragma unroll
    for (int g = 0; g < 16; g++) {
        uint2 u = synP[(size_t)g * NPT + t];  // 512 B contiguous per wave-load
        float w0 = __uint_as_float(u.x << 16);
        float w1 = __uint_as_float(u.x & 0xffff0000u);
        float w2 = __uint_as_float(u.y << 16);
        float w3 = __uint_as_float(u.y & 0xffff0000u);
        int a = g >> 2, b = g & 3;
        const float* nrow = PBin + ((size_t)(i + a) * NS_Q + (j + b)) * NS_R + k;
        acc += w0 * nrow[0] + w1 * nrow[1] + w2 * nrow[2] + w3 * nrow[3];
    }
    PBout[((size_t)i * NS_Q + j) * NS_R + k] = acc > 0.f ? acc * 3.6f : 0.f;
}

// ---------------- layer 1 split-K partials (PB holds 4*v5; 0.25 folded into fc23)
// exact r9 form: single NT stream, KSPLIT=8
__global__ __launch_bounds__(256) void gemv1(const float* __restrict__ W1,
                                             const float* __restrict__ PB,
                                             float* __restrict__ partial) {
    int n = blockIdx.x >> 3;        // 0..1023
    int c = blockIdx.x & 7;         // chunk 0..7
    const fx4* w4 = (const fx4*)(W1 + (size_t)n * (P_PER_ROW * 4));
    float a0 = 0.f, a1 = 0.f, a2 = 0.f, a3 = 0.f;
#pragma unroll 5
    for (int it = 0; it < P_CHUNK / 256; it++) {
        int p = c * P_CHUNK + it * 256 + threadIdx.x;
        fx4 w = __builtin_nontemporal_load(&w4[p]);
        float s = (w.x + w.y) + (w.z + w.w);
        int iloc = p >> 12;
        int j = (p >> 6) & 63;
        int k = p & 63;
        int base = ((iloc + 2) * NS_Q + (j + 2)) * NS_R + (k + 2);
        a0 += s * PB[base];
        a1 += s * PB[base + PB_SLAB];
        a2 += s * PB[base + 2 * PB_SLAB];
        a3 += s * PB[base + 3 * PB_SLAB];
    }
#pragma unroll
    for (int off = 32; off; off >>= 1) {
        a0 += __shfl_down(a0, off);
        a1 += __shfl_down(a1, off);
        a2 += __shfl_down(a2, off);
        a3 += __shfl_down(a3, off);
    }
    __shared__ float red[4][4];
    int lane = threadIdx.x & 63, wv = threadIdx.x >> 6;
    if (lane == 0) { red[wv][0] = a0; red[wv][1] = a1; red[wv][2] = a2; red[wv][3] = a3; }
    __syncthreads();
    if (threadIdx.x < 4) {
        int r = threadIdx.x;
        float s = (red[0][r] + red[1][r]) + (red[2][r] + red[3][r]);
        partial[((size_t)c * 4 + r) * 1024 + n] = s;
    }
}

// ---------------- fused fc2+fc3 (single block): h1,h2 staged in LDS
__global__ __launch_bounds__(256) void fc23(const float* __restrict__ W2,
                                            const float* __restrict__ b1,
                                            const float* __restrict__ b2,
                                            const float* __restrict__ W3,
                                            const float* __restrict__ b3,
                                            const float* __restrict__ partial,
                                            float* __restrict__ out) {
    __shared__ float h1s[4][1024];   // 16 KB
    __shared__ float h2s[4][128];    // 2 KB
    // phase 1: h1[r][e] = relu(0.25*sum_c partial + b1)
    for (int idx = threadIdx.x; idx < 4096; idx += 256) {
        int r = idx >> 10, e = idx & 1023;
        float acc = 0.f;
#pragma unroll
        for (int cc = 0; cc < KSPLIT; cc++) acc += partial[(cc * 4 + r) * 1024 + e];
        float h = 0.25f * acc + b1[e];
        h1s[r][e] = h > 0.f ? h : 0.f;
    }
    __syncthreads();
    // phase 2: h2[r][n] = relu(W2[n,:].h1[r,:] + b2[n])  (512 outputs, 2/thread)
    for (int idx = threadIdx.x; idx < 512; idx += 256) {
        int r = idx >> 7, n = idx & 127;
        const float* w = W2 + (size_t)n * 1024;
        float c0 = 0.f, c1 = 0.f, c2 = 0.f, c3 = 0.f;
        for (int e = 0; e < 1024; e += 4) {
            c0 += w[e] * h1s[r][e];
            c1 += w[e + 1] * h1s[r][e + 1];
            c2 += w[e + 2] * h1s[r][e + 2];
            c3 += w[e + 3] * h1s[r][e + 3];
        }
        float acc = ((c0 + c1) + (c2 + c3)) + b2[n];
        h2s[r][n] = acc > 0.f ? acc : 0.f;
    }
    __syncthreads();
    // phase 3: out[r*10+n]
    if (threadIdx.x < 40) {
        int r = threadIdx.x / 10, n = threadIdx.x % 10;
        float a = b3[n];
        for (int e = 0; e < 128; e++) a += W3[(size_t)n * 128 + e] * h2s[r][e];
        out[threadIdx.x] = a;
    }
}

extern "C" void kernel_launch(void* const* d_in, const int* in_sizes, int n_in,
                              void* d_out, int out_size, void* d_ws, size_t ws_size,
                              hipStream_t stream) {
    const float* vin = (const float*)d_in[0];
    const float* syn = (const float*)d_in[1];
    const float* W1  = (const float*)d_in[2];
    const float* b1  = (const float*)d_in[3];
    const float* W2  = (const float*)d_in[4];
    const float* b2  = (const float*)d_in[5];
    const float* W3  = (const float*)d_in[6];
    const float* b3  = (const float*)d_in[7];
    float* out = (float*)d_out;

    float* ws = (float*)d_ws;
    float* PB0 = ws;                       // 295936
    float* PB1 = PB0 + NS_SZ;              // 295936
    float* partial = PB1 + NS_SZ;          // 32*1024
    uint2* synP = (uint2*)(partial + 32 * 1024); // NPT*16 uint2 = 31.5 MB

    prologue<<<NS_BLOCKS + TR_BLOCKS, 256, 0, stream>>>(vin, syn, PB0, PB1, synP);
    float* cur = PB0; float* nxt = PB1;
    for (int it = 0; it < 5; it++) {
        conv_kernel<<<PT_BLOCKS, 256, 0, stream>>>(cur, synP, nxt);
        float* tmp = cur; cur = nxt; nxt = tmp;
    }
    // cur holds 4*v5 in padded layout
    gemv1<<<1024 * KSPLIT, 256, 0, stream>>>(W1, cur, partial);
    fc23<<<1, 256, 0, stream>>>(W2, b1, b2, W3, b3, partial, out);
}

// Round 15
// 253.434 us; speedup vs baseline: 1.2182x; 1.2182x over previous
//
#include <hip/hip_runtime.h>

#define DSX 60
#define SZ  64
#define NPT (DSX*SZ*SZ)        // 245760 points
#define NS_P 64
#define NS_Q 68
#define NS_R 68
#define NS_SZ (NS_P*NS_Q*NS_R) // 295936
#define P_PER_ROW 61440        // 245760/4 (float4 groups per W1 row)
#define KSPLIT 8
#define P_CHUNK (P_PER_ROW / KSPLIT)   // 7680
#define PB_SLAB (15*NS_Q*NS_R)         // 69360 (row-batch stride in PB)
#define NS_BLOCKS 1156                 // ceil(NS_SZ/256)
#define TR_BLOCKS (NPT / 64)           // 3840

typedef float fx4 __attribute__((ext_vector_type(4)));

__device__ __forceinline__ unsigned rne_bf16(float x) {
    unsigned b = __float_as_uint(x);
    return (b + 0x7fffu + ((b >> 16) & 1u)) >> 16;   // round-to-nearest-even bf16
}

// ---------------- fused prologue:
// blocks [0, NS_BLOCKS): PB0 = channel-sum(vinput) in ns layout; PB1 = 0
// blocks [NS_BLOCKS, NS_BLOCKS+TR_BLOCKS): syn transpose+pack to bf16 g-major
__global__ __launch_bounds__(256) void prologue(const float* __restrict__ vin,
                                                const float* __restrict__ syn,
                                                float* __restrict__ PB0,
                                                float* __restrict__ PB1,
                                                uint2* __restrict__ synP) {
    if (blockIdx.x < NS_BLOCKS) {
        int t = blockIdx.x * 256 + threadIdx.x;
        if (t >= NS_SZ) return;
        int r = t % NS_R;
        int q = (t / NS_R) % NS_Q;
        int p = t / (NS_R * NS_Q);
        float val = 0.f;
        if (p >= 2 && p < 62 && q >= 2 && q < 66 && r >= 2 && r < 66) {
            const float* b = vin + ((((size_t)(p - 2) * SZ) + (q - 2)) * SZ + (r - 2)) * 4;
            val = (b[0] + b[1]) + (b[2] + b[3]);
        }
        PB0[t] = val;
        PB1[t] = 0.f;
    } else {
        __shared__ float tile[64 * 65];
        int t0 = (blockIdx.x - NS_BLOCKS) * 64;
        const fx4* s4 = (const fx4*)syn;
#pragma unroll
        for (int r = 0; r < 4; r++) {
            int idx = r * 256 + threadIdx.x;      // 0..1023
            int pl = idx >> 4, g = idx & 15;
            fx4 v = s4[(size_t)(t0 + pl) * 16 + g];
            int base = pl * 65 + g * 4;
            tile[base] = v.x; tile[base + 1] = v.y; tile[base + 2] = v.z; tile[base + 3] = v.w;
        }
        __syncthreads();
        int l = threadIdx.x & 63;
        int wv = threadIdx.x >> 6; // 0..3
#pragma unroll
        for (int r = 0; r < 4; r++) {
            int g = r * 4 + wv;
            int base = l * 65 + g * 4;
            uint2 u;
            u.x = rne_bf16(tile[base])     | (rne_bf16(tile[base + 1]) << 16);
            u.y = rne_bf16(tile[base + 2]) | (rne_bf16(tile[base + 3]) << 16);
            synP[(size_t)g * NPT + t0 + l] = u;
        }
    }
}

// ---------------- conv: core = <bf16 weights, PBin neighborhood>, coalesced 8B weight loads
// PBout interior = 4 * 0.9 * relu(core)  (borders untouched -> stay 0)
__global__ __launch_bounds__(256) void conv_kernel(const float* __restrict__ PBin,
                                                   const uint2* __restrict__ synP,
                                                   float* __restrict__ PBout) {
    int t = blockIdx.x * 256 + threadIdx.x;   // 960 blocks exactly covers NPT
    int k = t & 63;
    int j = (t >> 6) & 63;
    int i = t >> 12;
    float acc = 0.f;
#pragma unroll
    for (int g = 0; g < 16; g++) {
        uint2 u = synP[(size_t)g * NPT + t];  // 512 B contiguous per wave-load
        float w0 = __uint_as_float(u.x << 16);
        float w1 = __uint_as_float(u.x & 0xffff0000u);
        float w2 = __uint_as_float(u.y << 16);
        float w3 = __uint_as_float(u.y & 0xffff0000u);
        int a = g >> 2, b = g & 3;
        const float* nrow = PBin + ((size_t)(i + a) * NS_Q + (j + b)) * NS_R + k;
        acc += w0 * nrow[0] + w1 * nrow[1] + w2 * nrow[2] + w3 * nrow[3];
    }
    PBout[((size_t)i * NS_Q + j) * NS_R + k] = acc > 0.f ? acc * 3.6f : 0.f;
}

// ---------------- layer 1 split-K partials (PB holds 4*v5; 0.25 folded into fc2)
__global__ __launch_bounds__(256) void gemv1(const float* __restrict__ W1,
                                             const float* __restrict__ PB,
                                             float* __restrict__ partial) {
    int n = blockIdx.x >> 3;        // 0..1023
    int c = blockIdx.x & 7;         // chunk 0..7
    const fx4* w4 = (const fx4*)(W1 + (size_t)n * (P_PER_ROW * 4));
    float a0 = 0.f, a1 = 0.f, a2 = 0.f, a3 = 0.f;
#pragma unroll 5
    for (int it = 0; it < P_CHUNK / 256; it++) {
        int p = c * P_CHUNK + it * 256 + threadIdx.x;
        fx4 w = __builtin_nontemporal_load(&w4[p]);
        float s = (w.x + w.y) + (w.z + w.w);
        int iloc = p >> 12;
        int j = (p >> 6) & 63;
        int k = p & 63;
        int base = ((iloc + 2) * NS_Q + (j + 2)) * NS_R + (k + 2);
        a0 += s * PB[base];
        a1 += s * PB[base + PB_SLAB];
        a2 += s * PB[base + 2 * PB_SLAB];
        a3 += s * PB[base + 3 * PB_SLAB];
    }
#pragma unroll
    for (int off = 32; off; off >>= 1) {
        a0 += __shfl_down(a0, off);
        a1 += __shfl_down(a1, off);
        a2 += __shfl_down(a2, off);
        a3 += __shfl_down(a3, off);
    }
    __shared__ float red[4][4];
    int lane = threadIdx.x & 63, wv = threadIdx.x >> 6;
    if (lane == 0) { red[wv][0] = a0; red[wv][1] = a1; red[wv][2] = a2; red[wv][3] = a3; }
    __syncthreads();
    if (threadIdx.x < 4) {
        int r = threadIdx.x;
        float s = (red[0][r] + red[1][r]) + (red[2][r] + red[3][r]);
        partial[((size_t)c * 4 + r) * 1024 + n] = s;
    }
}

// ---------------- layer 2: recombine split-K partials, relu(h1), then gemv vs W2
__global__ __launch_bounds__(256) void fc2(const float* __restrict__ W2,
                                           const float* __restrict__ b1,
                                           const float* __restrict__ b2,
                                           const float* __restrict__ partial,
                                           float* __restrict__ h2) {
    int n = blockIdx.x; // 0..127
    float a0 = 0.f, a1 = 0.f, a2 = 0.f, a3 = 0.f;
    for (int e = threadIdx.x; e < 1024; e += 256) {
        float w = W2[(size_t)n * 1024 + e];
        float be = b1[e];
#pragma unroll
        for (int r = 0; r < 4; r++) {
            float acc = 0.f;
#pragma unroll
            for (int cc = 0; cc < KSPLIT; cc++) acc += partial[(cc * 4 + r) * 1024 + e];
            float h = 0.25f * acc + be;
            h = h > 0.f ? h : 0.f;
            if (r == 0) a0 += w * h;
            else if (r == 1) a1 += w * h;
            else if (r == 2) a2 += w * h;
            else a3 += w * h;
        }
    }
#pragma unroll
    for (int off = 32; off; off >>= 1) {
        a0 += __shfl_down(a0, off);
        a1 += __shfl_down(a1, off);
        a2 += __shfl_down(a2, off);
        a3 += __shfl_down(a3, off);
    }
    __shared__ float red[4][4];
    int lane = threadIdx.x & 63, wv = threadIdx.x >> 6;
    if (lane == 0) { red[wv][0] = a0; red[wv][1] = a1; red[wv][2] = a2; red[wv][3] = a3; }
    __syncthreads();
    if (threadIdx.x < 4) {
        int r = threadIdx.x;
        float s = (red[0][r] + red[1][r]) + (red[2][r] + red[3][r]) + b2[n];
        h2[(size_t)r * 128 + n] = s > 0.f ? s : 0.f;
    }
}

// ---------------- layer 3: out[r*10+n] = sum_e W3[n,e]*h2[r,e] + b3[n]
__global__ __launch_bounds__(64) void fc3(const float* __restrict__ W3,
                                          const float* __restrict__ b3,
                                          const float* __restrict__ h2,
                                          float* __restrict__ out) {
    int t = threadIdx.x;
    if (t < 40) {
        int r = t / 10, n = t % 10;
        float a = b3[n];
        for (int e = 0; e < 128; e++) a += W3[(size_t)n * 128 + e] * h2[(size_t)r * 128 + e];
        out[t] = a;
    }
}

extern "C" void kernel_launch(void* const* d_in, const int* in_sizes, int n_in,
                              void* d_out, int out_size, void* d_ws, size_t ws_size,
                              hipStream_t stream) {
    const float* vin = (const float*)d_in[0];
    const float* syn = (const float*)d_in[1];
    const float* W1  = (const float*)d_in[2];
    const float* b1  = (const float*)d_in[3];
    const float* W2  = (const float*)d_in[4];
    const float* b2  = (const float*)d_in[5];
    const float* W3  = (const float*)d_in[6];
    const float* b3  = (const float*)d_in[7];
    float* out = (float*)d_out;

    float* ws = (float*)d_ws;
    float* PB0 = ws;                     // 295936
    float* PB1 = PB0 + NS_SZ;            // 295936
    float* partial = PB1 + NS_SZ;        // 32*1024
    float* h2 = partial + 32 * 1024;     // 512 (padded to 1024)
    uint2* synP = (uint2*)(h2 + 1024);   // NPT*16 uint2 = 31.5 MB, 8B-aligned

    const int ptBlocks = NPT / 256;      // 960

    prologue<<<NS_BLOCKS + TR_BLOCKS, 256, 0, stream>>>(vin, syn, PB0, PB1, synP);
    float* cur = PB0; float* nxt = PB1;
    for (int it = 0; it < 5; it++) {
        conv_kernel<<<ptBlocks, 256, 0, stream>>>(cur, synP, nxt);
        float* tmp = cur; cur = nxt; nxt = tmp;
    }
    // cur holds 4*v5 in padded layout
    gemv1<<<1024 * KSPLIT, 256, 0, stream>>>(W1, cur, partial);
    fc2<<<128, 256, 0, stream>>>(W2, b1, b2, partial, h2);
    fc3<<<1, 64, 0, stream>>>(W3, b3, h2, out);
}